// Round 3
// baseline (117.001 us; speedup 1.0000x reference)
//
#include <hip/hip_runtime.h>
#include <hip/hip_bf16.h>

#define DIMC 512
#define BATCH 4
#define SEQ 4096
#define NHEAD 8
#define HD 64
#define M_TOK (BATCH*SEQ)   // 16384
#define N_QKV (3*DIMC)      // 1536

typedef __bf16 bfv8 __attribute__((ext_vector_type(8)));
typedef float f32v4 __attribute__((ext_vector_type(4)));
typedef unsigned short u16v8 __attribute__((ext_vector_type(8)));

#define VMCNT(n) asm volatile("s_waitcnt vmcnt(" #n ")" ::: "memory")
#define LGKM0()  asm volatile("s_waitcnt lgkmcnt(0)" ::: "memory")

static __device__ __forceinline__ float bf2f(unsigned short u) {
    union { unsigned int i; float f; } x; x.i = ((unsigned int)u) << 16; return x.f;
}
static __device__ __forceinline__ unsigned short f2bf(float f) {
    union { float f; unsigned int i; } x; x.f = f;
    unsigned int r = x.i + 0x7FFFu + ((x.i >> 16) & 1u);
    return (unsigned short)(r >> 16);
}

static __device__ __forceinline__ void gload_lds16(const void* g, void* s) {
    __builtin_amdgcn_global_load_lds(
        (const __attribute__((address_space(1))) unsigned int*)g,
        (__attribute__((address_space(3))) unsigned int*)s, 16, 0, 0);
}

// ---------------- fp32 -> bf16 conversion ----------------
__global__ __launch_bounds__(256) void cvt_f32_bf16(
    const float* __restrict__ in, unsigned short* __restrict__ out, int n8)
{
    int i = blockIdx.x * blockDim.x + threadIdx.x;
    if (i >= n8) return;
    const float4* p = (const float4*)in + (size_t)i * 2;
    float4 a = p[0], b = p[1];
    u16v8 o;
    o[0] = f2bf(a.x); o[1] = f2bf(a.y); o[2] = f2bf(a.z); o[3] = f2bf(a.w);
    o[4] = f2bf(b.x); o[5] = f2bf(b.y); o[6] = f2bf(b.z); o[7] = f2bf(b.w);
    *(u16v8*)(out + (size_t)i * 8) = o;
}

// ------------- 8-phase 256x256 NT MFMA GEMM (m201-style, plain HIP) --------
// C[M][N] = A[M][K] * B[N][K]^T + bias.  BK=64, 8 waves (2Mx4N), 512 thr.
// LDS: 2 dbuf x [256][64] per matrix = 128 KiB. st_16x32 swizzle both-sides.
// Pipeline: stage A(t+1) at phases 1-2, B(t+2) at phases 3-4, vmcnt(4) once
// per K-tile (counted, never 0 in steady state).
template<bool OUT_BF16>
__global__ __launch_bounds__(512, 2) void gemm_nt_8ph(
    const unsigned short* __restrict__ A,  // [M][K] bf16
    const unsigned short* __restrict__ B,  // [N][K] bf16
    const float* __restrict__ bias,        // [N]
    void* __restrict__ Cout,
    int M, int N, int K)
{
    __shared__ __align__(16) unsigned short As[2][16384];
    __shared__ __align__(16) unsigned short Bs[2][16384];
    const int tid  = threadIdx.x;
    const int lane = tid & 63;
    const int wid  = tid >> 6;       // 0..7
    const int wm   = wid >> 2;       // 0..1  -> rows [wm*128, +128)
    const int wn   = wid & 3;        // 0..3  -> cols [wn*64, +64)
    const int m0 = blockIdx.x * 256;
    const int n0 = blockIdx.y * 256;
    const int frow = lane & 15;
    const int fcol = (lane >> 4) * 8;
    const int NT = K >> 6;

    f32v4 acc[8][4] = {};
    bfv8 aF[4][2], bF[4][2];

    // stage one 128-row half (h) of a [256][64] K-tile (tt) of matrix src
    // into ldsbuf. Linear LDS dest + inverse-swizzled global source (rule 21).
    auto STAGE = [&](const unsigned short* __restrict__ src, int row0, int tt,
                     int h, unsigned short* ldsbuf) {
        #pragma unroll
        for (int s = 0; s < 2; ++s) {
            int e  = h * 8192 + (tid + s * 512) * 8;       // elem offset in buffer
            int se = e ^ (((e >> 8) & 1) << 4);            // st_16x32 swizzle
            gload_lds16(src + (size_t)(row0 + (se >> 6)) * K + tt * 64 + (se & 63),
                        ldsbuf + h * 8192 + s * 4096 + wid * 512); // wave-uniform
        }
    };
    // swizzled fragment read: logical (row, col) -> ds_read_b128
    auto LDF = [&](const unsigned short* buf, int row, int col) -> bfv8 {
        int e = row * 64 + col;
        e ^= ((e >> 8) & 1) << 4;
        return *(const bfv8*)(buf + e);
    };

#define MFMA16(qm, nlo)                                                        \
    _Pragma("unroll") for (int i_ = 0; i_ < 4; ++i_)                           \
    _Pragma("unroll") for (int n_ = 0; n_ < 2; ++n_)                           \
    _Pragma("unroll") for (int k_ = 0; k_ < 2; ++k_)                           \
        acc[(qm)*4 + i_][(nlo) + n_] = __builtin_amdgcn_mfma_f32_16x16x32_bf16( \
            aF[i_][k_], bF[(nlo) + n_][k_], acc[(qm)*4 + i_][(nlo) + n_], 0, 0, 0);

    // prologue: B(t0), A(t0), B(t1) -> 12 loads/thread; wait t0 complete.
    STAGE(B, n0, 0, 0, Bs[0]);
    STAGE(B, n0, 0, 1, Bs[0]);
    STAGE(A, m0, 0, 0, As[0]);
    STAGE(A, m0, 0, 1, As[0]);
    STAGE(B, n0, 1, 0, Bs[1]);
    STAGE(B, n0, 1, 1, Bs[1]);
    VMCNT(4);
    __builtin_amdgcn_s_barrier();

    for (int t = 0; t < NT; ++t) {
        const int p = t & 1;
        const unsigned short* Ab = As[p];
        const unsigned short* Bb = Bs[p];
        // ---- P1: read A m0-3 + B n0-1 (12 ds_read); stage A-h0(t+1)
        #pragma unroll
        for (int i = 0; i < 4; ++i)
            #pragma unroll
            for (int ks = 0; ks < 2; ++ks)
                aF[i][ks] = LDF(Ab, wm * 128 + i * 16 + frow, ks * 32 + fcol);
        #pragma unroll
        for (int n = 0; n < 2; ++n)
            #pragma unroll
            for (int ks = 0; ks < 2; ++ks)
                bF[n][ks] = LDF(Bb, wn * 64 + n * 16 + frow, ks * 32 + fcol);
        if (t + 1 < NT) STAGE(A, m0, t + 1, 0, As[(t + 1) & 1]);
        __builtin_amdgcn_s_barrier();
        LGKM0(); __builtin_amdgcn_sched_barrier(0);
        __builtin_amdgcn_s_setprio(1);
        MFMA16(0, 0);
        __builtin_amdgcn_s_setprio(0);
        __builtin_amdgcn_s_barrier();
        // ---- P2: read B n2-3 (4); stage A-h1(t+1)
        #pragma unroll
        for (int n = 0; n < 2; ++n)
            #pragma unroll
            for (int ks = 0; ks < 2; ++ks)
                bF[2 + n][ks] = LDF(Bb, wn * 64 + (2 + n) * 16 + frow, ks * 32 + fcol);
        if (t + 1 < NT) STAGE(A, m0, t + 1, 1, As[(t + 1) & 1]);
        __builtin_amdgcn_s_barrier();
        LGKM0(); __builtin_amdgcn_sched_barrier(0);
        __builtin_amdgcn_s_setprio(1);
        MFMA16(0, 2);
        __builtin_amdgcn_s_setprio(0);
        __builtin_amdgcn_s_barrier();
        // ---- P3: read A m4-7 (8, reuse regs); stage B-h0(t+2)
        #pragma unroll
        for (int i = 0; i < 4; ++i)
            #pragma unroll
            for (int ks = 0; ks < 2; ++ks)
                aF[i][ks] = LDF(Ab, wm * 128 + 64 + i * 16 + frow, ks * 32 + fcol);
        if (t + 2 < NT) STAGE(B, n0, t + 2, 0, Bs[p]);
        __builtin_amdgcn_s_barrier();
        LGKM0(); __builtin_amdgcn_sched_barrier(0);
        __builtin_amdgcn_s_setprio(1);
        MFMA16(1, 0);
        __builtin_amdgcn_s_setprio(0);
        __builtin_amdgcn_s_barrier();
        // ---- P4: no reads; stage B-h1(t+2); counted vmcnt; barrier
        if (t + 2 < NT) STAGE(B, n0, t + 2, 1, Bs[p]);
        __builtin_amdgcn_s_barrier();
        LGKM0(); __builtin_amdgcn_sched_barrier(0);
        __builtin_amdgcn_s_setprio(1);
        MFMA16(1, 2);
        __builtin_amdgcn_s_setprio(0);
        if (t + 2 < NT) { VMCNT(4); } else { VMCNT(0); }
        __builtin_amdgcn_s_barrier();
    }
#undef MFMA16

    // epilogue: D row = (lane>>4)*4 + r, col = lane&15
    const int erow = (lane >> 4) * 4;
    const int ecol = lane & 15;
    #pragma unroll
    for (int ni = 0; ni < 4; ++ni) {
        const int col = n0 + wn * 64 + ni * 16 + ecol;
        const float bv = bias[col];
        #pragma unroll
        for (int mi = 0; mi < 8; ++mi) {
            const int rbase = m0 + wm * 128 + mi * 16 + erow;
            #pragma unroll
            for (int r = 0; r < 4; ++r) {
                const float v = acc[mi][ni][r] + bv;
                if constexpr (OUT_BF16)
                    ((unsigned short*)Cout)[(size_t)(rbase + r) * N + col] = f2bf(v);
                else
                    ((float*)Cout)[(size_t)(rbase + r) * N + col] = v;
            }
        }
    }
}

// ---------------- per-token 8x8 head-mix attention ----------------
// Writes Y2 scrambled: y[b][h*512 + (n>>3)][(n&7)*64 + d] so gemm_out is plain NT.
__global__ __launch_bounds__(64) void attn_mix(
    const unsigned short* __restrict__ Y1, // [16384][1536] bf16
    unsigned short* __restrict__ Y2)       // [16384][512]  bf16 (scrambled)
{
    __shared__ float s[8 * 1540];
    const int t = threadIdx.x;
    const size_t base = (size_t)blockIdx.x * 8 * N_QKV;
    #pragma unroll
    for (int i = 0; i < 24; ++i) {
        int v = i * 64 + t;
        int off = v * 8;
        int row = off / N_QKV;
        int col = off - row * N_QKV;
        ushort4 u0 = *(const ushort4*)(Y1 + base + off);
        ushort4 u1 = *(const ushort4*)(Y1 + base + off + 4);
        float* d = s + row * 1540 + col;
        d[0] = bf2f(u0.x); d[1] = bf2f(u0.y); d[2] = bf2f(u0.z); d[3] = bf2f(u0.w);
        d[4] = bf2f(u1.x); d[5] = bf2f(u1.y); d[6] = bf2f(u1.z); d[7] = bf2f(u1.w);
    }
    __syncthreads();
    const int tok = t >> 3, h = t & 7;
    const float* qp = s + tok * 1540 + h * HD;
    const float* kp = s + tok * 1540 + DIMC;
    const float* vp = s + tok * 1540 + 2 * DIMC;
    float sc[8];
    #pragma unroll
    for (int g = 0; g < 8; ++g) {
        float a = 0.f;
        const float* kg = kp + g * HD;
        #pragma unroll
        for (int i = 0; i < HD; ++i) {
            int d = (i + t) & 63;
            a = fmaf(qp[d], kg[d], a);
        }
        sc[g] = a * 0.125f;
    }
    float mx = sc[0];
    #pragma unroll
    for (int g = 1; g < 8; ++g) mx = fmaxf(mx, sc[g]);
    float sum = 0.f;
    #pragma unroll
    for (int g = 0; g < 8; ++g) { sc[g] = __expf(sc[g] - mx); sum += sc[g]; }
    float inv = 1.f / sum;
    #pragma unroll
    for (int g = 0; g < 8; ++g) sc[g] *= inv;

    const int tokg = blockIdx.x * 8 + tok;
    const int n = tokg & (SEQ - 1);
    const int b = tokg >> 12;
    const size_t drow = (size_t)b * SEQ + h * 512 + (n >> 3);
    unsigned short* dst = Y2 + drow * DIMC + ((n & 7) << 6);
    #pragma unroll
    for (int d0 = 0; d0 < HD; d0 += 8) {
        float o[8];
        #pragma unroll
        for (int j = 0; j < 8; ++j) {
            float a = 0.f;
            #pragma unroll
            for (int g = 0; g < 8; ++g)
                a = fmaf(sc[g], vp[g * HD + d0 + j], a);
            o[j] = a;
        }
        ushort4 o0, o1;
        o0.x = f2bf(o[0]); o0.y = f2bf(o[1]); o0.z = f2bf(o[2]); o0.w = f2bf(o[3]);
        o1.x = f2bf(o[4]); o1.y = f2bf(o[5]); o1.z = f2bf(o[6]); o1.w = f2bf(o[7]);
        *(ushort4*)(dst + d0) = o0;
        *(ushort4*)(dst + d0 + 4) = o1;
    }
}

extern "C" void kernel_launch(void* const* d_in, const int* in_sizes, int n_in,
                              void* d_out, int out_size, void* d_ws, size_t ws_size,
                              hipStream_t stream) {
    const float* x     = (const float*)d_in[0];
    const float* qkv_w = (const float*)d_in[1];
    const float* qkv_b = (const float*)d_in[2];
    const float* out_w = (const float*)d_in[3];
    const float* out_b = (const float*)d_in[4];
    float* out = (float*)d_out;

    unsigned short* Y1 = (unsigned short*)d_ws;            // 50.3 MB
    unsigned short* Xb = Y1 + (size_t)M_TOK * N_QKV;       // 16.8 MB
    unsigned short* Y2 = Xb;   // overlay: Xb dead before attn_mix writes Y2
    unsigned short* Wq = Xb + (size_t)M_TOK * DIMC;
    unsigned short* Wo = Wq + (size_t)N_QKV * DIMC;

    cvt_f32_bf16<<<(M_TOK * DIMC / 8 + 255) / 256, 256, 0, stream>>>(x, Xb, M_TOK * DIMC / 8);
    cvt_f32_bf16<<<(N_QKV * DIMC / 8 + 255) / 256, 256, 0, stream>>>(qkv_w, Wq, N_QKV * DIMC / 8);
    cvt_f32_bf16<<<(DIMC * DIMC / 8 + 255) / 256, 256, 0, stream>>>(out_w, Wo, DIMC * DIMC / 8);

    gemm_nt_8ph<true><<<dim3(M_TOK / 256, N_QKV / 256), 512, 0, stream>>>(
        Xb, Wq, qkv_b, Y1, M_TOK, N_QKV, DIMC);

    attn_mix<<<dim3(M_TOK / 8), 64, 0, stream>>>(Y1, Y2);

    gemm_nt_8ph<false><<<dim3(M_TOK / 256, DIMC / 256), 512, 0, stream>>>(
        Y2, Wo, out_b, out, M_TOK, DIMC, DIMC);
}